// Round 1
// baseline (2279.855 us; speedup 1.0000x reference)
//
#include <hip/hip_runtime.h>
#include <hip/hip_bf16.h>

#define HDIM 256
#define BR 8
#define SEQ 120
#define WARM 96
#define FLEN 24

// ws layout (floats): [0, 262144) = W_T2 [k][j][g]; [262144, 263168) = bb[j*4+g]; [263168, 264192) = wi[j*4+g]
#define WT2_OFF 0
#define BB_OFF  262144
#define WI_OFF  263168

__device__ __forceinline__ float fast_sig(float x) {
    return 1.0f / (1.0f + __expf(-x));
}
__device__ __forceinline__ float fast_tanh(float x) {
    // tanh(x) = 1 - 2/(exp(2x)+1); saturates correctly at +/-inf
    return 1.0f - 2.0f / (__expf(2.0f * x) + 1.0f);
}

__global__ __launch_bounds__(256) void lstm_prep(
    const float* __restrict__ W_ih, const float* __restrict__ W_hh,
    const float* __restrict__ b_ih, const float* __restrict__ b_hh,
    float* __restrict__ ws)
{
    int tid = blockIdx.x * 256 + threadIdx.x;
    if (tid < 262144) {
        // source-coalesced: tid = row*256 + k, row = g*256 + j
        int row = tid >> 8;
        int k   = tid & 255;
        int g   = row >> 8;
        int jj  = row & 255;
        ws[WT2_OFF + k * 1024 + jj * 4 + g] = W_hh[tid];
    }
    if (tid < 1024) {
        int jj = tid >> 2, g = tid & 3;
        int src = g * 256 + jj;
        ws[BB_OFF + tid] = b_ih[src] + b_hh[src];
        ws[WI_OFF + tid] = W_ih[src];
    }
}

__global__ __launch_bounds__(256, 1) void lstm_main(
    const float* __restrict__ x, const float* __restrict__ h0,
    const float* __restrict__ c0, const float* __restrict__ ws,
    const float* __restrict__ fcw, const float* __restrict__ fcb,
    float* __restrict__ out)
{
    __shared__ float h_lds[HDIM][BR];    // h transposed: [k][r], 8KB
    __shared__ float x_lds[BR][SEQ];     // block's input slice
    __shared__ float part[4][BR];        // per-wave y partials

    const int t  = threadIdx.x;
    const int j  = t;                    // hidden unit owned by this thread
    const int r0 = blockIdx.x * BR;

    // ---- init state ----
    #pragma unroll
    for (int r = 0; r < BR; ++r) h_lds[j][r] = h0[(r0 + r) * HDIM + j];
    float c[BR];
    #pragma unroll
    for (int r = 0; r < BR; ++r) c[r] = c0[(r0 + r) * HDIM + j];
    for (int idx = t; idx < BR * SEQ; idx += 256) {
        int r = idx / SEQ, s = idx % SEQ;
        x_lds[r][s] = x[(r0 + r) * SEQ + s];
    }

    const float4* __restrict__ w4 = (const float4*)(ws + WT2_OFF); // [k][j] as float4
    const float4 wiv = ((const float4*)(ws + WI_OFF))[j];
    const float4 bbv = ((const float4*)(ws + BB_OFF))[j];
    const float fcwj = fcw[j];
    const float fcbv = fcb[0];

    float y[BR];
    #pragma unroll
    for (int r = 0; r < BR; ++r) y[r] = 0.0f;

    __syncthreads();

    for (int step = 0; step < SEQ; ++step) {
        float acc0[BR], acc1[BR], acc2[BR], acc3[BR];
        #pragma unroll
        for (int r = 0; r < BR; ++r) {
            float in_r = (step < WARM) ? x_lds[r][step] : y[r];
            acc0[r] = bbv.x + in_r * wiv.x;
            acc1[r] = bbv.y + in_r * wiv.y;
            acc2[r] = bbv.z + in_r * wiv.z;
            acc3[r] = bbv.w + in_r * wiv.w;
        }

        // ---- k-loop: gates += h @ W^T, software-pipelined W prefetch ----
        float4 wcur0 = w4[0 * 256 + j];
        float4 wcur1 = w4[1 * 256 + j];
        float4 wcur2 = w4[2 * 256 + j];
        float4 wcur3 = w4[3 * 256 + j];
        #pragma unroll 1
        for (int kb = 0; kb < HDIM; kb += 4) {
            int kn = (kb + 4 < HDIM) ? (kb + 4) : kb;  // last iter re-reads (harmless)
            float4 wn0 = w4[(kn + 0) * 256 + j];
            float4 wn1 = w4[(kn + 1) * 256 + j];
            float4 wn2 = w4[(kn + 2) * 256 + j];
            float4 wn3 = w4[(kn + 3) * 256 + j];
            #pragma unroll
            for (int u = 0; u < 4; ++u) {
                int k = kb + u;
                float4 ha = *(const float4*)&h_lds[k][0];
                float4 hb = *(const float4*)&h_lds[k][4];
                float hk[8] = {ha.x, ha.y, ha.z, ha.w, hb.x, hb.y, hb.z, hb.w};
                float4 wk = (u == 0) ? wcur0 : (u == 1) ? wcur1 : (u == 2) ? wcur2 : wcur3;
                #pragma unroll
                for (int r = 0; r < BR; ++r) {
                    acc0[r] = fmaf(hk[r], wk.x, acc0[r]);
                    acc1[r] = fmaf(hk[r], wk.y, acc1[r]);
                    acc2[r] = fmaf(hk[r], wk.z, acc2[r]);
                    acc3[r] = fmaf(hk[r], wk.w, acc3[r]);
                }
            }
            wcur0 = wn0; wcur1 = wn1; wcur2 = wn2; wcur3 = wn3;
        }

        const bool needy = (step >= WARM - 1);

        __syncthreads();  // all reads of h_lds for this step done

        // ---- elementwise LSTM update (thread-local) ----
        float hn[BR];
        #pragma unroll
        for (int r = 0; r < BR; ++r) {
            float ig = fast_sig(acc0[r]);
            float fg = fast_sig(acc1[r]);
            float gg = fast_tanh(acc2[r]);
            float og = fast_sig(acc3[r]);
            float cn = fg * c[r] + ig * gg;
            c[r] = cn;
            hn[r] = og * fast_tanh(cn);
            h_lds[j][r] = hn[r];
        }

        // ---- fc head: y[r] = sum_j fcw[j]*hn[r][j] + fcb ----
        if (needy) {
            float v[BR];
            #pragma unroll
            for (int r = 0; r < BR; ++r) v[r] = fcwj * hn[r];
            #pragma unroll
            for (int off = 32; off > 0; off >>= 1) {
                #pragma unroll
                for (int r = 0; r < BR; ++r) v[r] += __shfl_down(v[r], off, 64);
            }
            int wave = t >> 6, lane = t & 63;
            if (lane == 0) {
                #pragma unroll
                for (int r = 0; r < BR; ++r) part[wave][r] = v[r];
            }
        }

        __syncthreads();  // h_lds writes (and part writes) visible

        if (needy) {
            #pragma unroll
            for (int r = 0; r < BR; ++r)
                y[r] = fcbv + part[0][r] + part[1][r] + part[2][r] + part[3][r];
            if (step >= WARM && t < BR)
                out[(r0 + t) * FLEN + (step - WARM)] =
                    fcbv + part[0][t] + part[1][t] + part[2][t] + part[3][t];
        }
    }
}

extern "C" void kernel_launch(void* const* d_in, const int* in_sizes, int n_in,
                              void* d_out, int out_size, void* d_ws, size_t ws_size,
                              hipStream_t stream) {
    const float* x    = (const float*)d_in[0];
    const float* h0   = (const float*)d_in[1];
    const float* c0   = (const float*)d_in[2];
    const float* W_ih = (const float*)d_in[3];
    const float* W_hh = (const float*)d_in[4];
    const float* b_ih = (const float*)d_in[5];
    const float* b_hh = (const float*)d_in[6];
    const float* fc_w = (const float*)d_in[7];
    const float* fc_b = (const float*)d_in[8];
    float* out = (float*)d_out;
    float* ws  = (float*)d_ws;

    lstm_prep<<<1024, 256, 0, stream>>>(W_ih, W_hh, b_ih, b_hh, ws);
    lstm_main<<<256, 256, 0, stream>>>(x, h0, c0, ws, fc_w, fc_b, out);
}